// Round 13
// baseline (1611.997 us; speedup 1.0000x reference)
//
#include <hip/hip_runtime.h>

typedef unsigned int u32;
typedef unsigned long long u64;
typedef __fp16 f16;
typedef __fp16 h2 __attribute__((ext_vector_type(2)));
typedef __fp16 h8 __attribute__((ext_vector_type(8)));
typedef float f32x2v __attribute__((ext_vector_type(2)));
typedef float f32x4v __attribute__((ext_vector_type(4)));
typedef float f32x16v __attribute__((ext_vector_type(16)));
typedef u32 u32x2v __attribute__((ext_vector_type(2)));
typedef u32 u32x4v __attribute__((ext_vector_type(4)));

static constexpr int BB = 64;     // batch
static constexpr int TT = 1024;   // seq len
static constexpr int HH = 256;    // hidden
static constexpr int GG = 768;    // 3*H
static constexpr size_t GI_BYTES = (size_t)BB * TT * GG * 2;  // f16 gi buffer

__device__ __forceinline__ u32 pk2(float a, float b) {
  h2 r = __builtin_amdgcn_cvt_pkrtz(a, b);
  return __builtin_bit_cast(u32, r);
}
__device__ __forceinline__ float dpp_x1(float x) {  // quad_perm [1,0,3,2]: pair swap
  return __builtin_bit_cast(float,
      __builtin_amdgcn_mov_dpp(__builtin_bit_cast(int, x), 0xB1, 0xF, 0xF, true));
}
__device__ __forceinline__ float sigf(float x) { return 1.f / (1.f + __expf(-x)); }
__device__ __forceinline__ float tanhf2(float x) {
  float e = __expf(2.f * x);
  return 1.f - 2.f / (e + 1.f);
}

// ---------------------------------------------------------------------------
// Phase 0: prepack W_hh into per-THREAD CONTIGUOUS f16x2 streams (r11 layout,
// passed correctness).  Thread j (u=j>>1, kh=j&1) owns gate rows {u,256+u,
// 512+u} over k-half [128kh,128kh+128); dword G*64+d = W[G*256+u][128kh+2d..].
// ---------------------------------------------------------------------------
__global__ void prepack_whh(const float* __restrict__ Whh, u32* __restrict__ Wp2) {
  int id = blockIdx.x * 256 + threadIdx.x;  // [0, 512*192)
  int j = id / 192;
  int rem = id - j * 192;
  int G = rem >> 6, d = rem & 63;
  int u = j >> 1, kh = j & 1;
  const float* p = Whh + (size_t)(G * 256 + u) * HH + 128 * kh + 2 * d;
  Wp2[id] = pk2(p[0], p[1]);
}

// ---------------------------------------------------------------------------
// Phase 1: gi = x @ W_ih^T + b_ih (+ b_hh folded for r,z), f16. (unchanged)
// ---------------------------------------------------------------------------
__device__ __forceinline__ f32x16v zero16() {
  f32x16v z;
#pragma unroll
  for (int i = 0; i < 16; ++i) z[i] = 0.f;
  return z;
}

__global__ __launch_bounds__(256, 2) void gemm_gi(
    const float* __restrict__ x, const float* __restrict__ Wih,
    const float* __restrict__ bih, const float* __restrict__ bhh,
    f16* __restrict__ gi) {
  __shared__ u32 bl[16384];  // 128 rows x 128 dwords (f16x2) = 64KB
  const int tid = threadIdx.x;
  const int lane = tid & 63;
  const int wv = tid >> 6;
  const int wr = wv >> 1, wc = wv & 1;
  const int l31 = lane & 31, lh = lane >> 5;
  const int m0 = blockIdx.x << 7;

  u32x4v afr[2][16];
#pragma unroll
  for (int fr = 0; fr < 2; ++fr) {
#pragma unroll
    for (int km = 0; km < 16; ++km) {
      int row = m0 + wr * 64 + fr * 32 + l31;
      int k0 = km * 16 + lh * 8;
      const f32x4v* p = (const f32x4v*)(x + (size_t)row * 256 + k0);
      f32x4v u = p[0], v = p[1];
      u32x4v t;
      t.x = pk2(u.x, u.y); t.y = pk2(u.z, u.w);
      t.z = pk2(v.x, v.y); t.w = pk2(v.z, v.w);
      afr[fr][km] = t;
    }
  }

  for (int nt = 0; nt < 6; ++nt) {
    const int n0 = nt << 7;
#pragma unroll
    for (int it = 0; it < 32; ++it) {
      int flat = it * 256 + tid;
      int r = flat >> 6;
      int q = flat & 63;
      f32x4v f = *(const f32x4v*)(Wih + (size_t)(n0 + r) * 256 + 4 * q);
      u32x2v pw;
      pw.x = pk2(f.x, f.y);
      pw.y = pk2(f.z, f.w);
      int wd = 2 * q;
      *(u32x2v*)&bl[r * 128 + (wd ^ ((r & 15) << 2))] = pw;
    }
    __syncthreads();

    f32x16v acc00 = zero16(), acc01 = zero16(), acc10 = zero16(), acc11 = zero16();
#pragma unroll
    for (int km = 0; km < 16; ++km) {
      int w0 = km * 8 + lh * 4;
      int rc0 = wc * 64 + l31;
      int rc1 = wc * 64 + 32 + l31;
      u32x4v b0 = *(const u32x4v*)&bl[rc0 * 128 + (w0 ^ ((rc0 & 15) << 2))];
      u32x4v b1 = *(const u32x4v*)&bl[rc1 * 128 + (w0 ^ ((rc1 & 15) << 2))];
      h8 a0h = __builtin_bit_cast(h8, afr[0][km]);
      h8 a1h = __builtin_bit_cast(h8, afr[1][km]);
      h8 b0h = __builtin_bit_cast(h8, b0);
      h8 b1h = __builtin_bit_cast(h8, b1);
      acc00 = __builtin_amdgcn_mfma_f32_32x32x16_f16(a0h, b0h, acc00, 0, 0, 0);
      acc10 = __builtin_amdgcn_mfma_f32_32x32x16_f16(a1h, b0h, acc10, 0, 0, 0);
      acc01 = __builtin_amdgcn_mfma_f32_32x32x16_f16(a0h, b1h, acc01, 0, 0, 0);
      acc11 = __builtin_amdgcn_mfma_f32_32x32x16_f16(a1h, b1h, acc11, 0, 0, 0);
    }

#define EPI(ACC, FR, FC)                                                      \
    {                                                                         \
      int gc = n0 + wc * 64 + (FC) * 32 + l31;                                \
      float bias = bih[gc] + (gc < 512 ? bhh[gc] : 0.f);                      \
      _Pragma("unroll")                                                       \
      for (int rg = 0; rg < 16; ++rg) {                                       \
        int gr = m0 + wr * 64 + (FR) * 32 + 4 * lh + (rg & 3) + 8 * (rg >> 2);\
        gi[(size_t)gr * 768 + gc] = (f16)(ACC[rg] + bias);                    \
      }                                                                       \
    }
    EPI(acc00, 0, 0) EPI(acc10, 1, 0) EPI(acc01, 0, 1) EPI(acc11, 1, 1)
#undef EPI
    __syncthreads();
  }
}

// ---------------------------------------------------------------------------
// Phase 2: recurrence, asm-core v3.
//  - weights in PHYSICAL v64..v255 (r12 loader, proven)
//  - ONE fused asm dot phase; 6 accumulation chains (2/gate)
//  - gi prefetched one step ahead (registers), consumed next iteration
//  - RAW barrier (s_waitcnt lgkmcnt(0); s_barrier): vmem (gi prefetch + out
//    stores) stays in flight across steps — no vmcnt(0) drain per step.
// 64 blocks x 512 thr (8 waves, 2/SIMD).  1 barrier/step.
// ---------------------------------------------------------------------------
#define WCLOB_LD \
  "v64","v65","v66","v67","v68","v69","v70","v71", \
  "v72","v73","v74","v75","v76","v77","v78","v79", \
  "v80","v81","v82","v83","v84","v85","v86","v87", \
  "v88","v89","v90","v91","v92","v93","v94","v95", \
  "v96","v97","v98","v99","v100","v101","v102","v103", \
  "v104","v105","v106","v107","v108","v109","v110","v111", \
  "v112","v113","v114","v115","v116","v117","v118","v119", \
  "v120","v121","v122","v123","v124","v125","v126","v127", \
  "v128","v129","v130","v131","v132","v133","v134","v135", \
  "v136","v137","v138","v139","v140","v141","v142","v143", \
  "v144","v145","v146","v147","v148","v149","v150","v151", \
  "v152","v153","v154","v155","v156","v157","v158","v159", \
  "v160","v161","v162","v163","v164","v165","v166","v167", \
  "v168","v169","v170","v171","v172","v173","v174","v175", \
  "v176","v177","v178","v179","v180","v181","v182","v183", \
  "v184","v185","v186","v187","v188","v189","v190","v191", \
  "v192","v193","v194","v195","v196","v197","v198","v199", \
  "v200","v201","v202","v203","v204","v205","v206","v207", \
  "v208","v209","v210","v211","v212","v213","v214","v215", \
  "v216","v217","v218","v219","v220","v221","v222","v223", \
  "v224","v225","v226","v227","v228","v229","v230","v231", \
  "v232","v233","v234","v235","v236","v237","v238","v239", \
  "v240","v241","v242","v243","v244","v245","v246","v247", \
  "v248","v249","v250","v251","v252","v253","v254","v255"

#define WCLOB "v56","v57","v58","v59","v60","v61","v62","v63", WCLOB_LD

#define LD16(A,B,OFF) "global_load_dwordx4 v[" #A ":" #B "], %0, off offset:" #OFF "\n\t"

#define RD_A(OFF) "ds_read_b128 v[56:59], %6 offset:" #OFF "\n\t"
#define RD_B(OFF) "ds_read_b128 v[60:63], %6 offset:" #OFF "\n\t"
#define WT1 "s_waitcnt lgkmcnt(1)\n\t"
#define WT0 "s_waitcnt lgkmcnt(0)\n\t"

// 12 dots: chains %0/%1 = r-gate, %2/%3 = z-gate, %4/%5 = n-gate
#define GRP(Q0,Q1,Q2,Q3, R0,R1,R2,R3, Z0,Z1,Z2,Z3, N0,N1,N2,N3) \
  "v_dot2_f32_f16 %0, v" #R0 ", v" #Q0 ", %0\n\t" \
  "v_dot2_f32_f16 %2, v" #Z0 ", v" #Q0 ", %2\n\t" \
  "v_dot2_f32_f16 %4, v" #N0 ", v" #Q0 ", %4\n\t" \
  "v_dot2_f32_f16 %1, v" #R1 ", v" #Q1 ", %1\n\t" \
  "v_dot2_f32_f16 %3, v" #Z1 ", v" #Q1 ", %3\n\t" \
  "v_dot2_f32_f16 %5, v" #N1 ", v" #Q1 ", %5\n\t" \
  "v_dot2_f32_f16 %0, v" #R2 ", v" #Q2 ", %0\n\t" \
  "v_dot2_f32_f16 %2, v" #Z2 ", v" #Q2 ", %2\n\t" \
  "v_dot2_f32_f16 %4, v" #N2 ", v" #Q2 ", %4\n\t" \
  "v_dot2_f32_f16 %1, v" #R3 ", v" #Q3 ", %1\n\t" \
  "v_dot2_f32_f16 %3, v" #Z3 ", v" #Q3 ", %3\n\t" \
  "v_dot2_f32_f16 %5, v" #N3 ", v" #Q3 ", %5\n\t"

__global__ __launch_bounds__(512, 2) void recur(
    const u32* __restrict__ Wp2, const f16* __restrict__ gi,
    const float* __restrict__ states, const float* __restrict__ mask,
    const float* __restrict__ bhh_g, float* __restrict__ out) {
  const int b = blockIdx.x;
  const int j = threadIdx.x;
  const int u = j >> 1;
  const int kh = j & 1;

  __shared__ __align__(16) u32 hbuf[2][128];   // h as f16x2
  __shared__ float mlds[TT];                   // mask row, 4 KB

  const float bhn = bhh_g[512 + u];   // r,z biases folded into gi by gemm

  const float* mk = mask + b * TT;
  const f16* gcur = gi + (size_t)b * TT * GG + u;
  float* outb = out + (size_t)b * TT * HH;

  for (int i = j; i < TT; i += 512) mlds[i] = mk[i];

  float hreg = states[b * HH + u] * mk[0];   // both lanes of the pair
  if (kh == 0) ((f16*)hbuf[0])[u] = (f16)hreg;

  // ---- load 192 weight dwords into PHYSICAL v64..v255 ----
  {
    u64 wa = (u64)(Wp2 + (size_t)j * 192);
    asm volatile(
      LD16(64,67,0)    LD16(68,71,16)   LD16(72,75,32)   LD16(76,79,48)
      LD16(80,83,64)   LD16(84,87,80)   LD16(88,91,96)   LD16(92,95,112)
      LD16(96,99,128)  LD16(100,103,144) LD16(104,107,160) LD16(108,111,176)
      LD16(112,115,192) LD16(116,119,208) LD16(120,123,224) LD16(124,127,240)
      LD16(128,131,256) LD16(132,135,272) LD16(136,139,288) LD16(140,143,304)
      LD16(144,147,320) LD16(148,151,336) LD16(152,155,352) LD16(156,159,368)
      LD16(160,163,384) LD16(164,167,400) LD16(168,171,416) LD16(172,175,432)
      LD16(176,179,448) LD16(180,183,464) LD16(184,187,480) LD16(188,191,496)
      LD16(192,195,512) LD16(196,199,528) LD16(200,203,544) LD16(204,207,560)
      LD16(208,211,576) LD16(212,215,592) LD16(216,219,608) LD16(220,223,624)
      LD16(224,227,640) LD16(228,231,656) LD16(232,235,672) LD16(236,239,688)
      LD16(240,243,704) LD16(244,247,720) LD16(248,251,736) LD16(252,255,752)
      "s_waitcnt vmcnt(0)\n\t"
      :: "v"(wa) : WCLOB_LD, "memory");
  }
  __syncthreads();

  float nh_prev = 0.f;
  // gi for step 0 (prefetched before the loop)
  f16 grc = gcur[0], gzc = gcur[256], gnc = gcur[512];

  for (int t = 0; t < TT; ++t) {
    // ---- prefetch NEXT step's gi (consumed next iteration; never drained) ----
    const f16* gnx = gcur + GG;       // at t=TT-1 overruns into Wp2 region: safe
    f16 grn = gnx[0], gzn = gnx[256], gnn = gnx[512];
    // deferred out store of step t-1 (ack never forced: raw barrier below)
    if (t > 0 && kh == 0) outb[(size_t)(t - 1) * HH + u] = nh_prev;

    u32 lds_addr = (u32)(size_t)(&hbuf[t & 1][kh << 6]);
    float ar0 = 0.f, ar1 = 0.f, az0 = 0.f, az1 = 0.f, an0 = 0.f, an1 = 0.f;

    asm volatile(
      WT0                      // drain C-side DS ops so counting is exact
      RD_A(0) RD_B(16)
      WT1 GRP(56,57,58,59,  64,65,66,67,    128,129,130,131, 192,193,194,195) RD_A(32)
      WT1 GRP(60,61,62,63,  68,69,70,71,    132,133,134,135, 196,197,198,199) RD_B(48)
      WT1 GRP(56,57,58,59,  72,73,74,75,    136,137,138,139, 200,201,202,203) RD_A(64)
      WT1 GRP(60,61,62,63,  76,77,78,79,    140,141,142,143, 204,205,206,207) RD_B(80)
      WT1 GRP(56,57,58,59,  80,81,82,83,    144,145,146,147, 208,209,210,211) RD_A(96)
      WT1 GRP(60,61,62,63,  84,85,86,87,    148,149,150,151, 212,213,214,215) RD_B(112)
      WT1 GRP(56,57,58,59,  88,89,90,91,    152,153,154,155, 216,217,218,219) RD_A(128)
      WT1 GRP(60,61,62,63,  92,93,94,95,    156,157,158,159, 220,221,222,223) RD_B(144)
      WT1 GRP(56,57,58,59,  96,97,98,99,    160,161,162,163, 224,225,226,227) RD_A(160)
      WT1 GRP(60,61,62,63,  100,101,102,103, 164,165,166,167, 228,229,230,231) RD_B(176)
      WT1 GRP(56,57,58,59,  104,105,106,107, 168,169,170,171, 232,233,234,235) RD_A(192)
      WT1 GRP(60,61,62,63,  108,109,110,111, 172,173,174,175, 236,237,238,239) RD_B(208)
      WT1 GRP(56,57,58,59,  112,113,114,115, 176,177,178,179, 240,241,242,243) RD_A(224)
      WT1 GRP(60,61,62,63,  116,117,118,119, 180,181,182,183, 244,245,246,247) RD_B(240)
      WT1 GRP(56,57,58,59,  120,121,122,123, 184,185,186,187, 248,249,250,251)
      WT0 GRP(60,61,62,63,  124,125,126,127, 188,189,190,191, 252,253,254,255)
      : "+v"(ar0), "+v"(ar1), "+v"(az0), "+v"(az1), "+v"(an0), "+v"(an1)
      : "v"(lds_addr)
      : WCLOB, "memory");

    const float mt = mlds[t];

    float ar = ar0 + ar1, az = az0 + az1, an = an0 + an1;
    // pair-reduce across the two k-halves (lane 2u <-> 2u+1)
    float ghr = ar + dpp_x1(ar);
    float ghz = az + dpp_x1(az);
    float ghn = an + dpp_x1(an);

    float r = sigf((float)grc + ghr);
    float z = sigf((float)gzc + ghz);
    float n = tanhf2((float)gnc + r * (ghn + bhn));
    float nh = z * (hreg - n) + n;            // (1-z)n + z h
    float hnew = hreg + mt * (nh - hreg);     // mask blend
    nh_prev = nh;
    hreg = hnew;
    if (kh == 0) ((f16*)hbuf[(t + 1) & 1])[u] = (f16)hnew;
    grc = grn; gzc = gzn; gnc = gnn;
    gcur += GG;

    // RAW barrier: drain LDS only; vmem (gi prefetch, out stores) stays in
    // flight across the step boundary.
    asm volatile("s_waitcnt lgkmcnt(0)\n\ts_barrier" ::: "memory");
  }

  if (kh == 0) {
    outb[(size_t)(TT - 1) * HH + u] = nh_prev;
    out[(size_t)BB * TT * HH + b * HH + u] = hreg;  // final state
  }
}

extern "C" void kernel_launch(void* const* d_in, const int* in_sizes, int n_in,
                              void* d_out, int out_size, void* d_ws, size_t ws_size,
                              hipStream_t stream) {
  const float* x      = (const float*)d_in[0];
  const float* states = (const float*)d_in[1];
  const float* mask   = (const float*)d_in[2];
  const float* W_ih   = (const float*)d_in[3];
  const float* W_hh   = (const float*)d_in[4];
  const float* b_ih   = (const float*)d_in[5];
  const float* b_hh   = (const float*)d_in[6];
  float* out = (float*)d_out;

  char* ws = (char*)d_ws;
  f16* gi = (f16*)ws;
  u32* Wp2 = (u32*)(ws + GI_BYTES);

  prepack_whh<<<dim3(384), dim3(256), 0, stream>>>(W_hh, Wp2);
  gemm_gi<<<dim3(512), dim3(256), 0, stream>>>(x, W_ih, b_ih, b_hh, gi);
  recur<<<dim3(64), dim3(512), 0, stream>>>(Wp2, gi, states, mask, b_hh, out);
}

// Round 14
// 1490.900 us; speedup vs baseline: 1.0812x; 1.0812x over previous
//
#include <hip/hip_runtime.h>

typedef unsigned int u32;
typedef unsigned long long u64;
typedef __fp16 f16;
typedef __fp16 h2 __attribute__((ext_vector_type(2)));
typedef __fp16 h8 __attribute__((ext_vector_type(8)));
typedef float f32x2v __attribute__((ext_vector_type(2)));
typedef float f32x4v __attribute__((ext_vector_type(4)));
typedef float f32x16v __attribute__((ext_vector_type(16)));
typedef u32 u32x2v __attribute__((ext_vector_type(2)));
typedef u32 u32x4v __attribute__((ext_vector_type(4)));

static constexpr int BB = 64;     // batch
static constexpr int TT = 1024;   // seq len
static constexpr int HH = 256;    // hidden
static constexpr int GG = 768;    // 3*H
static constexpr size_t GI_BYTES = (size_t)BB * TT * GG * 2;  // f16 gi buffer

__device__ __forceinline__ u32 pk2(float a, float b) {
  h2 r = __builtin_amdgcn_cvt_pkrtz(a, b);
  return __builtin_bit_cast(u32, r);
}
__device__ __forceinline__ float dpp_x1(float x) {  // quad_perm [1,0,3,2]
  return __builtin_bit_cast(float,
      __builtin_amdgcn_mov_dpp(__builtin_bit_cast(int, x), 0xB1, 0xF, 0xF, true));
}
__device__ __forceinline__ float dpp_x2(float x) {  // quad_perm [2,3,0,1]
  return __builtin_bit_cast(float,
      __builtin_amdgcn_mov_dpp(__builtin_bit_cast(int, x), 0x4E, 0xF, 0xF, true));
}
__device__ __forceinline__ float qred(float x) {    // sum over quad (kc lanes)
  x += dpp_x1(x);
  x += dpp_x2(x);
  return x;
}
__device__ __forceinline__ float sigf(float x) { return 1.f / (1.f + __expf(-x)); }
__device__ __forceinline__ float tanhf2(float x) {
  float e = __expf(2.f * x);
  return 1.f - 2.f / (e + 1.f);
}

// ---------------------------------------------------------------------------
// Phase 0: prepack W_hh for the 6-row x 64-k tiling.
// Thread j: rg=j>>2 owns units {2rg,2rg+1} x 3 gates; kc=j&3 owns
// k in [64kc, 64kc+64).  Weight dword i (0..191): m=i/24 (h-chunk),
// e=(i%24)/6 (dword in chunk), rs=i%6 (G=rs>>1, uu=rs&1):
//   row = G*256 + 2rg + uu ;  k = 64kc + 8m + 2e
// Wp2[j*192 + i] = pk2(W[row][k], W[row][k+1]) — contiguous per thread.
// ---------------------------------------------------------------------------
__global__ void prepack_whh(const float* __restrict__ Whh, u32* __restrict__ Wp2) {
  int id = blockIdx.x * 256 + threadIdx.x;  // [0, 512*192)
  int j = id / 192;
  int i = id - j * 192;
  int m = i / 24;
  int r24 = i - m * 24;
  int e = r24 / 6;
  int rs = r24 - e * 6;
  int G = rs >> 1, uu = rs & 1;
  int rg = j >> 2, kc = j & 3;
  int row = G * 256 + 2 * rg + uu;
  int k = 64 * kc + 8 * m + 2 * e;
  const float* p = Whh + (size_t)row * HH + k;
  Wp2[id] = pk2(p[0], p[1]);
}

// ---------------------------------------------------------------------------
// Phase 1: gi = x @ W_ih^T + b_ih (+ b_hh folded for r,z), f16. (unchanged)
// ---------------------------------------------------------------------------
__device__ __forceinline__ f32x16v zero16() {
  f32x16v z;
#pragma unroll
  for (int i = 0; i < 16; ++i) z[i] = 0.f;
  return z;
}

__global__ __launch_bounds__(256, 2) void gemm_gi(
    const float* __restrict__ x, const float* __restrict__ Wih,
    const float* __restrict__ bih, const float* __restrict__ bhh,
    f16* __restrict__ gi) {
  __shared__ u32 bl[16384];  // 128 rows x 128 dwords (f16x2) = 64KB
  const int tid = threadIdx.x;
  const int lane = tid & 63;
  const int wv = tid >> 6;
  const int wr = wv >> 1, wc = wv & 1;
  const int l31 = lane & 31, lh = lane >> 5;
  const int m0 = blockIdx.x << 7;

  u32x4v afr[2][16];
#pragma unroll
  for (int fr = 0; fr < 2; ++fr) {
#pragma unroll
    for (int km = 0; km < 16; ++km) {
      int row = m0 + wr * 64 + fr * 32 + l31;
      int k0 = km * 16 + lh * 8;
      const f32x4v* p = (const f32x4v*)(x + (size_t)row * 256 + k0);
      f32x4v u = p[0], v = p[1];
      u32x4v t;
      t.x = pk2(u.x, u.y); t.y = pk2(u.z, u.w);
      t.z = pk2(v.x, v.y); t.w = pk2(v.z, v.w);
      afr[fr][km] = t;
    }
  }

  for (int nt = 0; nt < 6; ++nt) {
    const int n0 = nt << 7;
#pragma unroll
    for (int it = 0; it < 32; ++it) {
      int flat = it * 256 + tid;
      int r = flat >> 6;
      int q = flat & 63;
      f32x4v f = *(const f32x4v*)(Wih + (size_t)(n0 + r) * 256 + 4 * q);
      u32x2v pw;
      pw.x = pk2(f.x, f.y);
      pw.y = pk2(f.z, f.w);
      int wd = 2 * q;
      *(u32x2v*)&bl[r * 128 + (wd ^ ((r & 15) << 2))] = pw;
    }
    __syncthreads();

    f32x16v acc00 = zero16(), acc01 = zero16(), acc10 = zero16(), acc11 = zero16();
#pragma unroll
    for (int km = 0; km < 16; ++km) {
      int w0 = km * 8 + lh * 4;
      int rc0 = wc * 64 + l31;
      int rc1 = wc * 64 + 32 + l31;
      u32x4v b0 = *(const u32x4v*)&bl[rc0 * 128 + (w0 ^ ((rc0 & 15) << 2))];
      u32x4v b1 = *(const u32x4v*)&bl[rc1 * 128 + (w0 ^ ((rc1 & 15) << 2))];
      h8 a0h = __builtin_bit_cast(h8, afr[0][km]);
      h8 a1h = __builtin_bit_cast(h8, afr[1][km]);
      h8 b0h = __builtin_bit_cast(h8, b0);
      h8 b1h = __builtin_bit_cast(h8, b1);
      acc00 = __builtin_amdgcn_mfma_f32_32x32x16_f16(a0h, b0h, acc00, 0, 0, 0);
      acc10 = __builtin_amdgcn_mfma_f32_32x32x16_f16(a1h, b0h, acc10, 0, 0, 0);
      acc01 = __builtin_amdgcn_mfma_f32_32x32x16_f16(a0h, b1h, acc01, 0, 0, 0);
      acc11 = __builtin_amdgcn_mfma_f32_32x32x16_f16(a1h, b1h, acc11, 0, 0, 0);
    }

#define EPI(ACC, FR, FC)                                                      \
    {                                                                         \
      int gc = n0 + wc * 64 + (FC) * 32 + l31;                                \
      float bias = bih[gc] + (gc < 512 ? bhh[gc] : 0.f);                      \
      _Pragma("unroll")                                                       \
      for (int rg = 0; rg < 16; ++rg) {                                       \
        int gr = m0 + wr * 64 + (FR) * 32 + 4 * lh + (rg & 3) + 8 * (rg >> 2);\
        gi[(size_t)gr * 768 + gc] = (f16)(ACC[rg] + bias);                    \
      }                                                                       \
    }
    EPI(acc00, 0, 0) EPI(acc10, 1, 0) EPI(acc01, 0, 1) EPI(acc11, 1, 1)
#undef EPI
    __syncthreads();
  }
}

// ---------------------------------------------------------------------------
// Phase 2: recurrence, asm-core v4.  6-row x 64-k tiling:
//  - 8 ds_read_b128/step (was 16), 4-deep pipeline (buffers v48..v63),
//    steady-state lgkmcnt(3) -> ~150cyc lead >= 120cyc LDS latency.
//  - h chunks padded to 144B stride: the 4 per-wave read addresses hit
//    disjoint bank sets (conflict-free); writes also conflict-free.
//  - weights in PHYSICAL v64..v255 (r12 loader, proven); 6 dot chains.
//  - r12 skeleton otherwise: in-step gi loads, deferred out store,
//    __syncthreads() per step.
// 64 blocks x 512 thr (8 waves, 2/SIMD).
// ---------------------------------------------------------------------------
#define WCLOB_LD \
  "v64","v65","v66","v67","v68","v69","v70","v71", \
  "v72","v73","v74","v75","v76","v77","v78","v79", \
  "v80","v81","v82","v83","v84","v85","v86","v87", \
  "v88","v89","v90","v91","v92","v93","v94","v95", \
  "v96","v97","v98","v99","v100","v101","v102","v103", \
  "v104","v105","v106","v107","v108","v109","v110","v111", \
  "v112","v113","v114","v115","v116","v117","v118","v119", \
  "v120","v121","v122","v123","v124","v125","v126","v127", \
  "v128","v129","v130","v131","v132","v133","v134","v135", \
  "v136","v137","v138","v139","v140","v141","v142","v143", \
  "v144","v145","v146","v147","v148","v149","v150","v151", \
  "v152","v153","v154","v155","v156","v157","v158","v159", \
  "v160","v161","v162","v163","v164","v165","v166","v167", \
  "v168","v169","v170","v171","v172","v173","v174","v175", \
  "v176","v177","v178","v179","v180","v181","v182","v183", \
  "v184","v185","v186","v187","v188","v189","v190","v191", \
  "v192","v193","v194","v195","v196","v197","v198","v199", \
  "v200","v201","v202","v203","v204","v205","v206","v207", \
  "v208","v209","v210","v211","v212","v213","v214","v215", \
  "v216","v217","v218","v219","v220","v221","v222","v223", \
  "v224","v225","v226","v227","v228","v229","v230","v231", \
  "v232","v233","v234","v235","v236","v237","v238","v239", \
  "v240","v241","v242","v243","v244","v245","v246","v247", \
  "v248","v249","v250","v251","v252","v253","v254","v255"

#define WCLOB \
  "v48","v49","v50","v51","v52","v53","v54","v55", \
  "v56","v57","v58","v59","v60","v61","v62","v63", WCLOB_LD

#define LD16(A,B,OFF) "global_load_dwordx4 v[" #A ":" #B "], %0, off offset:" #OFF "\n\t"

#define RD0(OFF) "ds_read_b128 v[48:51], %6 offset:" #OFF "\n\t"
#define RD1(OFF) "ds_read_b128 v[52:55], %6 offset:" #OFF "\n\t"
#define RD2(OFF) "ds_read_b128 v[56:59], %6 offset:" #OFF "\n\t"
#define RD3(OFF) "ds_read_b128 v[60:63], %6 offset:" #OFF "\n\t"
#define WT3 "s_waitcnt lgkmcnt(3)\n\t"
#define WT2 "s_waitcnt lgkmcnt(2)\n\t"
#define WT1 "s_waitcnt lgkmcnt(1)\n\t"
#define WT0 "s_waitcnt lgkmcnt(0)\n\t"

// 6 dots of one q-dword against 6 weight regs (chains %0..%5 = r0,r1,z0,z1,n0,n1)
#define D6(Q, W0,W1,W2,W3,W4,W5) \
  "v_dot2_f32_f16 %0, v" #W0 ", v" #Q ", %0\n\t" \
  "v_dot2_f32_f16 %1, v" #W1 ", v" #Q ", %1\n\t" \
  "v_dot2_f32_f16 %2, v" #W2 ", v" #Q ", %2\n\t" \
  "v_dot2_f32_f16 %3, v" #W3 ", v" #Q ", %3\n\t" \
  "v_dot2_f32_f16 %4, v" #W4 ", v" #Q ", %4\n\t" \
  "v_dot2_f32_f16 %5, v" #W5 ", v" #Q ", %5\n\t"

__global__ __launch_bounds__(512, 2) void recur(
    const u32* __restrict__ Wp2, const f16* __restrict__ gi,
    const float* __restrict__ states, const float* __restrict__ mask,
    const float* __restrict__ bhh_g, float* __restrict__ out) {
  const int b = blockIdx.x;
  const int j = threadIdx.x;
  const int rg = j >> 2;            // row-group: units 2rg, 2rg+1
  const int kc = j & 3;             // k-chunk [64kc, 64kc+64)
  const int u2 = 2 * rg;

  __shared__ __align__(16) u32 hbuf[2][144];  // 4 chunks x 144B (128B h + 16B pad)
  __shared__ float mlds[TT];                  // mask row, 4 KB

  const f32x2v bn2 = *(const f32x2v*)(bhh_g + 512 + u2);  // n-gate bias pair

  const float* mk = mask + b * TT;
  const f16* gcur = gi + (size_t)b * TT * GG;
  float* outb = out + (size_t)b * TT * HH;

  for (int i = j; i < TT; i += 512) mlds[i] = mk[i];

  const float mk0 = mk[0];
  float hreg0 = states[b * HH + u2] * mk0;       // all 4 kc lanes redundant
  float hreg1 = states[b * HH + u2 + 1] * mk0;
  if (j < 256) {  // init h chunk layout: value v -> byte (v>>6)*144 + (v&63)*2
    float hv = states[b * HH + j] * mk0;
    ((f16*)hbuf[0])[(j >> 6) * 72 + (j & 63)] = (f16)hv;
  }

  // ---- load 192 weight dwords into PHYSICAL v64..v255 ----
  {
    u64 wa = (u64)(Wp2 + (size_t)j * 192);
    asm volatile(
      LD16(64,67,0)    LD16(68,71,16)   LD16(72,75,32)   LD16(76,79,48)
      LD16(80,83,64)   LD16(84,87,80)   LD16(88,91,96)   LD16(92,95,112)
      LD16(96,99,128)  LD16(100,103,144) LD16(104,107,160) LD16(108,111,176)
      LD16(112,115,192) LD16(116,119,208) LD16(120,123,224) LD16(124,127,240)
      LD16(128,131,256) LD16(132,135,272) LD16(136,139,288) LD16(140,143,304)
      LD16(144,147,320) LD16(148,151,336) LD16(152,155,352) LD16(156,159,368)
      LD16(160,163,384) LD16(164,167,400) LD16(168,171,416) LD16(172,175,432)
      LD16(176,179,448) LD16(180,183,464) LD16(184,187,480) LD16(188,191,496)
      LD16(192,195,512) LD16(196,199,528) LD16(200,203,544) LD16(204,207,560)
      LD16(208,211,576) LD16(212,215,592) LD16(216,219,608) LD16(220,223,624)
      LD16(224,227,640) LD16(228,231,656) LD16(232,235,672) LD16(236,239,688)
      LD16(240,243,704) LD16(244,247,720) LD16(248,251,736) LD16(252,255,752)
      "s_waitcnt vmcnt(0)\n\t"
      :: "v"(wa) : WCLOB_LD, "memory");
  }
  __syncthreads();

  float nh_prev0 = 0.f, nh_prev1 = 0.f;

  for (int t = 0; t < TT; ++t) {
    if (t > 0 && kc == 0) {
      f32x2v o; o.x = nh_prev0; o.y = nh_prev1;
      *(f32x2v*)(outb + (size_t)(t - 1) * HH + u2) = o;
    }
    // gi for this step: pairs (u2, u2+1) per gate, consumed at gate phase
    const f16* gt = gcur + (size_t)t * GG;
    h2 g_r = *(const h2*)(gt + u2);
    h2 g_z = *(const h2*)(gt + 256 + u2);
    h2 g_n = *(const h2*)(gt + 512 + u2);

    u32 lds_addr = (u32)(size_t)(&hbuf[t & 1][0]) + kc * 144;
    float ar0 = 0.f, ar1 = 0.f, az0 = 0.f, az1 = 0.f, an0 = 0.f, an1 = 0.f;

    asm volatile(
      WT0                       // drain C-side DS ops so counting is exact
      RD0(0) RD1(16) RD2(32) RD3(48)
      // group 0 (chunk 0, buf A), issue chunk 4 into A
      WT3
      D6(48, 64,65,66,67,68,69) D6(49, 70,71,72,73,74,75)
      D6(50, 76,77,78,79,80,81) D6(51, 82,83,84,85,86,87)
      RD0(64)
      WT3
      D6(52, 88,89,90,91,92,93) D6(53, 94,95,96,97,98,99)
      D6(54, 100,101,102,103,104,105) D6(55, 106,107,108,109,110,111)
      RD1(80)
      WT3
      D6(56, 112,113,114,115,116,117) D6(57, 118,119,120,121,122,123)
      D6(58, 124,125,126,127,128,129) D6(59, 130,131,132,133,134,135)
      RD2(96)
      WT3
      D6(60, 136,137,138,139,140,141) D6(61, 142,143,144,145,146,147)
      D6(62, 148,149,150,151,152,153) D6(63, 154,155,156,157,158,159)
      RD3(112)
      WT3
      D6(48, 160,161,162,163,164,165) D6(49, 166,167,168,169,170,171)
      D6(50, 172,173,174,175,176,177) D6(51, 178,179,180,181,182,183)
      WT2
      D6(52, 184,185,186,187,188,189) D6(53, 190,191,192,193,194,195)
      D6(54, 196,197,198,199,200,201) D6(55, 202,203,204,205,206,207)
      WT1
      D6(56, 208,209,210,211,212,213) D6(57, 214,215,216,217,218,219)
      D6(58, 220,221,222,223,224,225) D6(59, 226,227,228,229,230,231)
      WT0
      D6(60, 232,233,234,235,236,237) D6(61, 238,239,240,241,242,243)
      D6(62, 244,245,246,247,248,249) D6(63, 250,251,252,253,254,255)
      : "+v"(ar0), "+v"(ar1), "+v"(az0), "+v"(az1), "+v"(an0), "+v"(an1)
      : "v"(lds_addr)
      : WCLOB, "memory");

    const float mt = mlds[t];

    // quad-reduce over the 4 k-chunks (kc lanes)
    float ghr0 = qred(ar0), ghr1 = qred(ar1);
    float ghz0 = qred(az0), ghz1 = qred(az1);
    float ghn0 = qred(an0), ghn1 = qred(an1);

    float r0 = sigf((float)g_r[0] + ghr0);
    float z0 = sigf((float)g_z[0] + ghz0);
    float n0 = tanhf2((float)g_n[0] + r0 * (ghn0 + bn2.x));
    float nh0 = z0 * (hreg0 - n0) + n0;
    hreg0 = hreg0 + mt * (nh0 - hreg0);

    float r1 = sigf((float)g_r[1] + ghr1);
    float z1 = sigf((float)g_z[1] + ghz1);
    float n1 = tanhf2((float)g_n[1] + r1 * (ghn1 + bn2.y));
    float nh1 = z1 * (hreg1 - n1) + n1;
    hreg1 = hreg1 + mt * (nh1 - hreg1);

    nh_prev0 = nh0; nh_prev1 = nh1;
    if (kc == 0)
      hbuf[(t + 1) & 1][(rg >> 5) * 36 + (rg & 31)] = pk2(hreg0, hreg1);
    __syncthreads();
  }

  if (kc == 0) {
    f32x2v o; o.x = nh_prev0; o.y = nh_prev1;
    *(f32x2v*)(outb + (size_t)(TT - 1) * HH + u2) = o;
    f32x2v hf; hf.x = hreg0; hf.y = hreg1;
    *(f32x2v*)(out + (size_t)BB * TT * HH + (size_t)b * HH + u2) = hf;
  }
}

extern "C" void kernel_launch(void* const* d_in, const int* in_sizes, int n_in,
                              void* d_out, int out_size, void* d_ws, size_t ws_size,
                              hipStream_t stream) {
  const float* x      = (const float*)d_in[0];
  const float* states = (const float*)d_in[1];
  const float* mask   = (const float*)d_in[2];
  const float* W_ih   = (const float*)d_in[3];
  const float* W_hh   = (const float*)d_in[4];
  const float* b_ih   = (const float*)d_in[5];
  const float* b_hh   = (const float*)d_in[6];
  float* out = (float*)d_out;

  char* ws = (char*)d_ws;
  f16* gi = (f16*)ws;
  u32* Wp2 = (u32*)(ws + GI_BYTES);

  prepack_whh<<<dim3(384), dim3(256), 0, stream>>>(W_hh, Wp2);
  gemm_gi<<<dim3(512), dim3(256), 0, stream>>>(x, W_ih, b_ih, b_hh, gi);
  recur<<<dim3(64), dim3(512), 0, stream>>>(Wp2, gi, states, mask, b_hh, out);
}